// Round 1
// baseline (1581.863 us; speedup 1.0000x reference)
//
#include <hip/hip_runtime.h>
#include <math.h>

#define D 64

// ---------------------------------------------------------------------------
// Kernel 1: degree accumulation. deg[0..N) = out-degree (src), deg[N..2N) = in-degree (dst)
// ---------------------------------------------------------------------------
__global__ void deg_kernel(const int* __restrict__ src, const int* __restrict__ dst,
                           float* __restrict__ deg, int E, int N) {
    int i = blockIdx.x * blockDim.x + threadIdx.x;
    if (i < E) {
        atomicAdd(&deg[src[i]], 1.0f);
        atomicAdd(&deg[N + dst[i]], 1.0f);
    }
}

// ---------------------------------------------------------------------------
// Kernel 2: deg -> clamp(deg,1)^-0.5  (in place, both halves at once)
// ---------------------------------------------------------------------------
__global__ void norm_kernel(float* __restrict__ deg, int twoN) {
    int i = blockIdx.x * blockDim.x + threadIdx.x;
    if (i < twoN) {
        float v = deg[i];
        v = v < 1.0f ? 1.0f : v;
        deg[i] = 1.0f / sqrtf(v);
    }
}

// ---------------------------------------------------------------------------
// Kernel 3: scatter-add. 16 threads per edge, each handles one float4 (4 feats).
// agg (= d_out) must be zeroed beforehand.
// ---------------------------------------------------------------------------
__global__ void scatter_kernel(const float* __restrict__ x, const int* __restrict__ src,
                               const int* __restrict__ dst, const float* __restrict__ norm_src,
                               float* __restrict__ agg, int E) {
    int tid = blockIdx.x * blockDim.x + threadIdx.x;
    int e = tid >> 4;   // edge index
    int q = tid & 15;   // which float4 of the 64-wide row
    if (e < E) {
        int s = src[e];
        int d = dst[e];
        float ns = norm_src[s];
        float4 v = reinterpret_cast<const float4*>(x)[s * (D / 4) + q];
        float* o = agg + (long long)d * D + q * 4;
        atomicAdd(o + 0, v.x * ns);
        atomicAdd(o + 1, v.y * ns);
        atomicAdd(o + 2, v.z * ns);
        atomicAdd(o + 3, v.w * ns);
    }
}

// ---------------------------------------------------------------------------
// Kernel 4: out[r,:] = (agg[r,:] * norm_dst[r]) @ W   (in place on d_out)
// W (64x64 = 16KB) staged in LDS. 256 threads = 4 rows x 64 feats per step.
// Each wave (64 lanes) owns one row -> rowS[sub][k] is a broadcast read.
// ---------------------------------------------------------------------------
__global__ __launch_bounds__(256) void gemm_kernel(float* __restrict__ out,
                                                   const float* __restrict__ W,
                                                   const float* __restrict__ norm_dst,
                                                   int N, int rows_per_block) {
    __shared__ float Ws[D * D];
    __shared__ float rowS[4][D];
    for (int i = threadIdx.x; i < D * D; i += 256) Ws[i] = W[i];

    int f   = threadIdx.x & 63;
    int sub = threadIdx.x >> 6;
    int base = blockIdx.x * rows_per_block;

    for (int r0 = 0; r0 < rows_per_block; r0 += 4) {
        int r = base + r0 + sub;
        bool valid = (r < N);
        __syncthreads();   // Ws ready (iter 0) / previous rowS reads done
        if (valid) {
            rowS[sub][f] = out[(long long)r * D + f] * norm_dst[r];
        }
        __syncthreads();
        if (valid) {
            float acc = 0.0f;
            #pragma unroll
            for (int k = 0; k < D; ++k) acc += rowS[sub][k] * Ws[k * D + f];
            out[(long long)r * D + f] = acc;
        }
    }
}

// ---------------------------------------------------------------------------
extern "C" void kernel_launch(void* const* d_in, const int* in_sizes, int n_in,
                              void* d_out, int out_size, void* d_ws, size_t ws_size,
                              hipStream_t stream) {
    const float* x   = (const float*)d_in[0];
    const float* W   = (const float*)d_in[1];
    const int*   src = (const int*)d_in[2];
    const int*   dst = (const int*)d_in[3];

    const int N = in_sizes[0] / D;      // 100000
    const int E = in_sizes[2];          // 1600000

    float* deg = (float*)d_ws;          // [0,N): norm_src, [N,2N): norm_dst (after norm_kernel)
    float* agg = (float*)d_out;         // agg accumulates in d_out, transformed in place

    // zero degree buffers and output accumulator (harness poisons with 0xAA)
    hipMemsetAsync(deg, 0, (size_t)2 * N * sizeof(float), stream);
    hipMemsetAsync(agg, 0, (size_t)N * D * sizeof(float), stream);

    // degrees
    deg_kernel<<<(E + 255) / 256, 256, 0, stream>>>(src, dst, deg, E, N);

    // norms (in place over both halves)
    norm_kernel<<<(2 * N + 255) / 256, 256, 0, stream>>>(deg, 2 * N);

    // scatter-add: 16 threads per edge
    long long scatter_threads = (long long)E * 16;
    int scatter_blocks = (int)((scatter_threads + 255) / 256);
    scatter_kernel<<<scatter_blocks, 256, 0, stream>>>(x, src, dst, deg, agg, E);

    // row-wise matmul with norm_dst fused
    const int rows_per_block = 64;
    int gemm_blocks = (N + rows_per_block - 1) / rows_per_block;
    gemm_kernel<<<gemm_blocks, 256, 0, stream>>>(agg, W, deg + N, N, rows_per_block);
}

// Round 2
// 420.280 us; speedup vs baseline: 3.7638x; 3.7638x over previous
//
#include <hip/hip_runtime.h>
#include <math.h>

#define D 64
#define SCAN_TILE 1024
#define SCAN_THREADS 256
#define SCAN_ITEMS 4

// ============================================================================
// FAST PATH: CSR-by-dst binning, then gather-aggregate (no float atomics)
// ============================================================================

// --- 1. int histogram: cnt[0..N) = out-degree(src), cnt[N..2N) = in-degree(dst)
__global__ void hist_kernel(const int* __restrict__ src, const int* __restrict__ dst,
                            int* __restrict__ cnt, int E, int N) {
    int i = blockIdx.x * blockDim.x + threadIdx.x;
    if (i < E) {
        atomicAdd(&cnt[src[i]], 1);
        atomicAdd(&cnt[N + dst[i]], 1);
    }
}

// --- 2. norm[i] = clamp(cnt[i],1)^-0.5
__global__ void norm_from_cnt_kernel(const int* __restrict__ cnt, float* __restrict__ norm,
                                     int twoN) {
    int i = blockIdx.x * blockDim.x + threadIdx.x;
    if (i < twoN) {
        int c = cnt[i];
        float v = (float)(c < 1 ? 1 : c);
        norm[i] = 1.0f / sqrtf(v);
    }
}

// --- 3a. per-block exclusive scan of cnt_dst, block totals -> partials
__global__ __launch_bounds__(SCAN_THREADS)
void scan_blocks_kernel(const int* __restrict__ cnt_dst, int* __restrict__ offsets,
                        int* __restrict__ partials, int N) {
    __shared__ int sdata[SCAN_THREADS];
    int t = threadIdx.x;
    int base = blockIdx.x * SCAN_TILE + t * SCAN_ITEMS;
    int v[SCAN_ITEMS];
    int sum = 0;
    #pragma unroll
    for (int i = 0; i < SCAN_ITEMS; ++i) {
        int idx = base + i;
        v[i] = (idx < N) ? cnt_dst[idx] : 0;
        sum += v[i];
    }
    sdata[t] = sum;
    __syncthreads();
    for (int off = 1; off < SCAN_THREADS; off <<= 1) {
        int val = (t >= off) ? sdata[t - off] : 0;
        __syncthreads();
        if (t >= off) sdata[t] += val;
        __syncthreads();
    }
    int excl = sdata[t] - sum;
    if (t == SCAN_THREADS - 1) partials[blockIdx.x] = sdata[t];
    int run = excl;
    #pragma unroll
    for (int i = 0; i < SCAN_ITEMS; ++i) {
        int idx = base + i;
        if (idx < N) offsets[idx] = run;
        run += v[i];
    }
}

// --- 3b. exclusive scan of block partials (single block; nblk <= SCAN_THREADS)
__global__ __launch_bounds__(SCAN_THREADS)
void scan_partials_kernel(int* __restrict__ partials, int nblk) {
    __shared__ int sdata[SCAN_THREADS];
    int t = threadIdx.x;
    int v = (t < nblk) ? partials[t] : 0;
    sdata[t] = v;
    __syncthreads();
    for (int off = 1; off < SCAN_THREADS; off <<= 1) {
        int val = (t >= off) ? sdata[t - off] : 0;
        __syncthreads();
        if (t >= off) sdata[t] += val;
        __syncthreads();
    }
    if (t < nblk) partials[t] = sdata[t] - v;
}

// --- 3c. add block bases back; init cursor; set offsets[N]=E
__global__ void add_back_kernel(int* __restrict__ offsets, int* __restrict__ cursor,
                                const int* __restrict__ partials, int N, int E) {
    int i = blockIdx.x * blockDim.x + threadIdx.x;
    if (i < N) {
        int o = offsets[i] + partials[i >> 10];  // SCAN_TILE == 1024
        offsets[i] = o;
        cursor[i] = o;
    }
    if (i == 0) offsets[N] = E;
}

// --- 4. bin edges by dst: sorted_src[pos] = src  (int atomics only)
__global__ void bin_kernel(const int* __restrict__ src, const int* __restrict__ dst,
                           int* __restrict__ cursor, int* __restrict__ sorted_src, int E) {
    int i = blockIdx.x * blockDim.x + threadIdx.x;
    if (i < E) {
        int pos = atomicAdd(&cursor[dst[i]], 1);
        sorted_src[pos] = src[i];
    }
}

// --- 5. fused aggregate + GEMM. One wave per dst row; lane = feature.
//        acc[f] = sum_{e in seg(r)} x[src_e, f] * norm_src[src_e]
//        out[r,f] = sum_k (acc[k]*norm_dst[r]) * W[k,f]   (acc[k] via __shfl)
__global__ __launch_bounds__(256)
void agg_gemm_kernel(const float* __restrict__ x, const int* __restrict__ offsets,
                     const int* __restrict__ sorted_src, const float* __restrict__ norm,
                     const float* __restrict__ W, float* __restrict__ out,
                     int N, int rows_per_block) {
    __shared__ float Ws[D * D];
    for (int i = threadIdx.x; i < D * D; i += 256) Ws[i] = W[i];
    __syncthreads();

    const float* norm_src = norm;
    const float* norm_dst = norm + N;

    int f   = threadIdx.x & 63;
    int sub = threadIdx.x >> 6;
    int base = blockIdx.x * rows_per_block;

    for (int r0 = sub; r0 < rows_per_block; r0 += 4) {
        int r = base + r0;
        if (r >= N) break;
        int beg = offsets[r];
        int end = offsets[r + 1];
        float acc = 0.0f;
        for (int j0 = beg; j0 < end; j0 += 64) {
            int e = j0 + f;
            int sv = 0;
            float nv = 0.0f;
            if (e < end) {
                sv = sorted_src[e];
                nv = norm_src[sv];
            }
            int cnt = end - j0;
            if (cnt > 64) cnt = 64;
            for (int t = 0; t < cnt; ++t) {
                int   s  = __shfl(sv, t);
                float ns = __shfl(nv, t);
                acc += x[(size_t)s * D + f] * ns;
            }
        }
        float av = acc * norm_dst[r];
        float o = 0.0f;
        #pragma unroll
        for (int k = 0; k < D; ++k) {
            o += __shfl(av, k) * Ws[k * D + f];
        }
        out[(size_t)r * D + f] = o;
    }
}

// ============================================================================
// FALLBACK PATH (round-0, proven): float-atomic scatter
// ============================================================================

__global__ void deg_kernel(const int* __restrict__ src, const int* __restrict__ dst,
                           float* __restrict__ deg, int E, int N) {
    int i = blockIdx.x * blockDim.x + threadIdx.x;
    if (i < E) {
        atomicAdd(&deg[src[i]], 1.0f);
        atomicAdd(&deg[N + dst[i]], 1.0f);
    }
}

__global__ void norm_kernel(float* __restrict__ deg, int twoN) {
    int i = blockIdx.x * blockDim.x + threadIdx.x;
    if (i < twoN) {
        float v = deg[i];
        v = v < 1.0f ? 1.0f : v;
        deg[i] = 1.0f / sqrtf(v);
    }
}

__global__ void scatter_kernel(const float* __restrict__ x, const int* __restrict__ src,
                               const int* __restrict__ dst, const float* __restrict__ norm_src,
                               float* __restrict__ agg, int E) {
    int tid = blockIdx.x * blockDim.x + threadIdx.x;
    int e = tid >> 4;
    int q = tid & 15;
    if (e < E) {
        int s = src[e];
        int d = dst[e];
        float ns = norm_src[s];
        float4 v = reinterpret_cast<const float4*>(x)[s * (D / 4) + q];
        float* o = agg + (long long)d * D + q * 4;
        atomicAdd(o + 0, v.x * ns);
        atomicAdd(o + 1, v.y * ns);
        atomicAdd(o + 2, v.z * ns);
        atomicAdd(o + 3, v.w * ns);
    }
}

__global__ __launch_bounds__(256) void gemm_kernel(float* __restrict__ out,
                                                   const float* __restrict__ W,
                                                   const float* __restrict__ norm_dst,
                                                   int N, int rows_per_block) {
    __shared__ float Ws[D * D];
    __shared__ float rowS[4][D];
    for (int i = threadIdx.x; i < D * D; i += 256) Ws[i] = W[i];

    int f   = threadIdx.x & 63;
    int sub = threadIdx.x >> 6;
    int base = blockIdx.x * rows_per_block;

    for (int r0 = 0; r0 < rows_per_block; r0 += 4) {
        int r = base + r0 + sub;
        bool valid = (r < N);
        __syncthreads();
        if (valid) rowS[sub][f] = out[(long long)r * D + f] * norm_dst[r];
        __syncthreads();
        if (valid) {
            float acc = 0.0f;
            #pragma unroll
            for (int k = 0; k < D; ++k) acc += rowS[sub][k] * Ws[k * D + f];
            out[(long long)r * D + f] = acc;
        }
    }
}

// ============================================================================
extern "C" void kernel_launch(void* const* d_in, const int* in_sizes, int n_in,
                              void* d_out, int out_size, void* d_ws, size_t ws_size,
                              hipStream_t stream) {
    const float* x   = (const float*)d_in[0];
    const float* W   = (const float*)d_in[1];
    const int*   src = (const int*)d_in[2];
    const int*   dst = (const int*)d_in[3];

    const int N = in_sizes[0] / D;   // 100000
    const int E = in_sizes[2];       // 1600000
    const int nblk = (N + SCAN_TILE - 1) / SCAN_TILE;

    // workspace layout (all 4-byte words)
    size_t w_norm = 0;                    // 2N floats
    size_t w_cnt  = w_norm + 2 * (size_t)N;   // 2N ints
    size_t w_offs = w_cnt  + 2 * (size_t)N;   // N+1 ints
    size_t w_cur  = w_offs + (size_t)N + 1;   // N ints
    size_t w_part = w_cur  + (size_t)N;       // SCAN_THREADS ints
    size_t w_sort = w_part + SCAN_THREADS;    // E ints
    size_t need_bytes = (w_sort + (size_t)E) * 4;

    bool fast = (ws_size >= need_bytes) && (nblk <= SCAN_THREADS);

    if (fast) {
        float* norm       = (float*)d_ws + w_norm;
        int*   cnt        = (int*)d_ws + w_cnt;
        int*   offsets    = (int*)d_ws + w_offs;
        int*   cursor     = (int*)d_ws + w_cur;
        int*   partials   = (int*)d_ws + w_part;
        int*   sorted_src = (int*)d_ws + w_sort;
        float* out        = (float*)d_out;

        hipMemsetAsync(cnt, 0, 2 * (size_t)N * sizeof(int), stream);

        hist_kernel<<<(E + 255) / 256, 256, 0, stream>>>(src, dst, cnt, E, N);
        norm_from_cnt_kernel<<<(2 * N + 255) / 256, 256, 0, stream>>>(cnt, norm, 2 * N);
        scan_blocks_kernel<<<nblk, SCAN_THREADS, 0, stream>>>(cnt + N, offsets, partials, N);
        scan_partials_kernel<<<1, SCAN_THREADS, 0, stream>>>(partials, nblk);
        add_back_kernel<<<(N + 255) / 256, 256, 0, stream>>>(offsets, cursor, partials, N, E);
        bin_kernel<<<(E + 255) / 256, 256, 0, stream>>>(src, dst, cursor, sorted_src, E);

        const int rows_per_block = 32;
        int blocks = (N + rows_per_block - 1) / rows_per_block;
        agg_gemm_kernel<<<blocks, 256, 0, stream>>>(x, offsets, sorted_src, norm, W, out,
                                                    N, rows_per_block);
    } else {
        float* deg = (float*)d_ws;
        float* agg = (float*)d_out;

        hipMemsetAsync(deg, 0, (size_t)2 * N * sizeof(float), stream);
        hipMemsetAsync(agg, 0, (size_t)N * D * sizeof(float), stream);

        deg_kernel<<<(E + 255) / 256, 256, 0, stream>>>(src, dst, deg, E, N);
        norm_kernel<<<(2 * N + 255) / 256, 256, 0, stream>>>(deg, 2 * N);

        long long scatter_threads = (long long)E * 16;
        int scatter_blocks = (int)((scatter_threads + 255) / 256);
        scatter_kernel<<<scatter_blocks, 256, 0, stream>>>(x, src, dst, deg, agg, E);

        const int rows_per_block = 64;
        int gemm_blocks = (N + rows_per_block - 1) / rows_per_block;
        gemm_kernel<<<gemm_blocks, 256, 0, stream>>>(agg, W, deg + N, N, rows_per_block);
    }
}

// Round 3
// 383.226 us; speedup vs baseline: 4.1278x; 1.0967x over previous
//
#include <hip/hip_runtime.h>
#include <math.h>

#define D 64
#define SCAN_TILE 1024
#define SCAN_THREADS 256
#define SCAN_ITEMS 4

// ============================================================================
// CSR prologue
// ============================================================================

// --- 1. int histogram, int4-vectorized: cnt[0..N)=out-deg(src), cnt[N..2N)=in-deg(dst)
__global__ void hist4_kernel(const int* __restrict__ src, const int* __restrict__ dst,
                             int* __restrict__ cnt, int E, int N) {
    int i = blockIdx.x * blockDim.x + threadIdx.x;
    int E4 = E >> 2;
    if (i < E4) {
        int4 s = reinterpret_cast<const int4*>(src)[i];
        int4 d = reinterpret_cast<const int4*>(dst)[i];
        atomicAdd(&cnt[s.x], 1); atomicAdd(&cnt[s.y], 1);
        atomicAdd(&cnt[s.z], 1); atomicAdd(&cnt[s.w], 1);
        atomicAdd(&cnt[N + d.x], 1); atomicAdd(&cnt[N + d.y], 1);
        atomicAdd(&cnt[N + d.z], 1); atomicAdd(&cnt[N + d.w], 1);
    }
    if (i == 0) {
        for (int e = E4 << 2; e < E; ++e) {
            atomicAdd(&cnt[src[e]], 1);
            atomicAdd(&cnt[N + dst[e]], 1);
        }
    }
}

// --- 2. norm[i] = clamp(cnt[i],1)^-0.5
__global__ void norm_from_cnt_kernel(const int* __restrict__ cnt, float* __restrict__ norm,
                                     int twoN) {
    int i = blockIdx.x * blockDim.x + threadIdx.x;
    if (i < twoN) {
        int c = cnt[i];
        float v = (float)(c < 1 ? 1 : c);
        norm[i] = 1.0f / sqrtf(v);
    }
}

// --- 3a. per-block exclusive scan of cnt_dst
__global__ __launch_bounds__(SCAN_THREADS)
void scan_blocks_kernel(const int* __restrict__ cnt_dst, int* __restrict__ offsets,
                        int* __restrict__ partials, int N) {
    __shared__ int sdata[SCAN_THREADS];
    int t = threadIdx.x;
    int base = blockIdx.x * SCAN_TILE + t * SCAN_ITEMS;
    int v[SCAN_ITEMS];
    int sum = 0;
    #pragma unroll
    for (int i = 0; i < SCAN_ITEMS; ++i) {
        int idx = base + i;
        v[i] = (idx < N) ? cnt_dst[idx] : 0;
        sum += v[i];
    }
    sdata[t] = sum;
    __syncthreads();
    for (int off = 1; off < SCAN_THREADS; off <<= 1) {
        int val = (t >= off) ? sdata[t - off] : 0;
        __syncthreads();
        if (t >= off) sdata[t] += val;
        __syncthreads();
    }
    int excl = sdata[t] - sum;
    if (t == SCAN_THREADS - 1) partials[blockIdx.x] = sdata[t];
    int run = excl;
    #pragma unroll
    for (int i = 0; i < SCAN_ITEMS; ++i) {
        int idx = base + i;
        if (idx < N) offsets[idx] = run;
        run += v[i];
    }
}

// --- 3b. exclusive scan of partials (single block)
__global__ __launch_bounds__(SCAN_THREADS)
void scan_partials_kernel(int* __restrict__ partials, int nblk) {
    __shared__ int sdata[SCAN_THREADS];
    int t = threadIdx.x;
    int v = (t < nblk) ? partials[t] : 0;
    sdata[t] = v;
    __syncthreads();
    for (int off = 1; off < SCAN_THREADS; off <<= 1) {
        int val = (t >= off) ? sdata[t - off] : 0;
        __syncthreads();
        if (t >= off) sdata[t] += val;
        __syncthreads();
    }
    if (t < nblk) partials[t] = sdata[t] - v;
}

// --- 3c. add back block bases; init cursor; offsets[N]=E
__global__ void add_back_kernel(int* __restrict__ offsets, int* __restrict__ cursor,
                                const int* __restrict__ partials, int N, int E) {
    int i = blockIdx.x * blockDim.x + threadIdx.x;
    if (i < N) {
        int o = offsets[i] + partials[i >> 10];  // SCAN_TILE == 1024
        offsets[i] = o;
        cursor[i] = o;
    }
    if (i == 0) offsets[N] = E;
}

// --- 4. bin edges by dst (int4-vectorized index reads)
__global__ void bin4_kernel(const int* __restrict__ src, const int* __restrict__ dst,
                            int* __restrict__ cursor, int* __restrict__ sorted_src, int E) {
    int i = blockIdx.x * blockDim.x + threadIdx.x;
    int E4 = E >> 2;
    if (i < E4) {
        int4 s = reinterpret_cast<const int4*>(src)[i];
        int4 d = reinterpret_cast<const int4*>(dst)[i];
        sorted_src[atomicAdd(&cursor[d.x], 1)] = s.x;
        sorted_src[atomicAdd(&cursor[d.y], 1)] = s.y;
        sorted_src[atomicAdd(&cursor[d.z], 1)] = s.z;
        sorted_src[atomicAdd(&cursor[d.w], 1)] = s.w;
    }
    if (i == 0) {
        for (int e = E4 << 2; e < E; ++e) {
            sorted_src[atomicAdd(&cursor[dst[e]], 1)] = src[e];
        }
    }
}

// ============================================================================
// Variant A: y = (x*norm_src)@W dense pass, then pure gather-sum aggregation
// ============================================================================

__global__ __launch_bounds__(256)
void xw_kernel(const float* __restrict__ x, const float* __restrict__ W,
               const float* __restrict__ norm_src, float* __restrict__ y, int N) {
    __shared__ float Ws[D * D];
    __shared__ float rowS[4][D];
    for (int i = threadIdx.x; i < D * D; i += 256) Ws[i] = W[i];
    int f   = threadIdx.x & 63;
    int sub = threadIdx.x >> 6;
    int base = blockIdx.x * 64;
    for (int r0 = 0; r0 < 64; r0 += 4) {
        int r = base + r0 + sub;
        bool valid = (r < N);
        __syncthreads();
        if (valid) rowS[sub][f] = x[(size_t)r * D + f] * norm_src[r];
        __syncthreads();
        if (valid) {
            float acc = 0.0f;
            #pragma unroll
            for (int k = 0; k < D; ++k) acc += rowS[sub][k] * Ws[k * D + f];
            y[(size_t)r * D + f] = acc;
        }
    }
}

// One wave per dst row. 16-lane groups each own one edge; lane&15 = float4 slot.
// out[r,:] = norm_dst[r] * sum_e y[src_e,:]
__global__ __launch_bounds__(256)
void agg_kernel(const float4* __restrict__ y4, const int* __restrict__ offsets,
                const int* __restrict__ sorted_src, const float* __restrict__ norm_dst,
                float4* __restrict__ out4, int N) {
    int wave = (blockIdx.x << 2) + (threadIdx.x >> 6);
    if (wave >= N) return;
    int lane = threadIdx.x & 63;
    int g = lane >> 4;
    int q = lane & 15;
    int beg = offsets[wave];
    int end = offsets[wave + 1];
    float nd = norm_dst[wave];
    float x0 = 0.f, x1 = 0.f, x2 = 0.f, x3 = 0.f;
    int j = beg + g;
    while (j + 4 < end) {   // 2x unroll: indices j and j+4 both valid
        int s0 = sorted_src[j];
        int s1 = sorted_src[j + 4];
        float4 v0 = y4[(size_t)s0 * 16 + q];
        float4 v1 = y4[(size_t)s1 * 16 + q];
        x0 += v0.x + v1.x;
        x1 += v0.y + v1.y;
        x2 += v0.z + v1.z;
        x3 += v0.w + v1.w;
        j += 8;
    }
    if (j < end) {
        int s = sorted_src[j];
        float4 v = y4[(size_t)s * 16 + q];
        x0 += v.x; x1 += v.y; x2 += v.z; x3 += v.w;
    }
    // cross-group reduce (groups 0..3 hold partial sums for the same q)
    x0 += __shfl_xor(x0, 16); x1 += __shfl_xor(x1, 16);
    x2 += __shfl_xor(x2, 16); x3 += __shfl_xor(x3, 16);
    x0 += __shfl_xor(x0, 32); x1 += __shfl_xor(x1, 32);
    x2 += __shfl_xor(x2, 32); x3 += __shfl_xor(x3, 32);
    if (lane < 16) {
        float4 o;
        o.x = x0 * nd; o.y = x1 * nd; o.z = x2 * nd; o.w = x3 * nd;
        out4[(size_t)wave * 16 + q] = o;
    }
}

// ============================================================================
// Variant B (if ws can't hold y): same agg structure, norm_src + W fused
// ============================================================================
__global__ __launch_bounds__(256)
void agg_gemm2_kernel(const float4* __restrict__ x4, const int* __restrict__ offsets,
                      const int* __restrict__ sorted_src, const float* __restrict__ norm,
                      const float* __restrict__ W, float* __restrict__ out, int N) {
    __shared__ float Ws[D * D];
    for (int i = threadIdx.x; i < D * D; i += 256) Ws[i] = W[i];
    __syncthreads();
    int wave = (blockIdx.x << 2) + (threadIdx.x >> 6);
    if (wave >= N) return;
    const float* norm_dst = norm + N;
    int lane = threadIdx.x & 63;
    int g = lane >> 4;
    int q = lane & 15;
    int beg = offsets[wave];
    int end = offsets[wave + 1];
    float x0 = 0.f, x1 = 0.f, x2 = 0.f, x3 = 0.f;
    int j = beg + g;
    while (j + 4 < end) {
        int s0 = sorted_src[j];
        int s1 = sorted_src[j + 4];
        float n0 = norm[s0];
        float n1 = norm[s1];
        float4 v0 = x4[(size_t)s0 * 16 + q];
        float4 v1 = x4[(size_t)s1 * 16 + q];
        x0 += v0.x * n0 + v1.x * n1;
        x1 += v0.y * n0 + v1.y * n1;
        x2 += v0.z * n0 + v1.z * n1;
        x3 += v0.w * n0 + v1.w * n1;
        j += 8;
    }
    if (j < end) {
        int s = sorted_src[j];
        float ns = norm[s];
        float4 v = x4[(size_t)s * 16 + q];
        x0 += v.x * ns; x1 += v.y * ns; x2 += v.z * ns; x3 += v.w * ns;
    }
    x0 += __shfl_xor(x0, 16); x1 += __shfl_xor(x1, 16);
    x2 += __shfl_xor(x2, 16); x3 += __shfl_xor(x3, 16);
    x0 += __shfl_xor(x0, 32); x1 += __shfl_xor(x1, 32);
    x2 += __shfl_xor(x2, 32); x3 += __shfl_xor(x3, 32);
    // GEMM epilogue: row[k] lives in lane (k>>2), component (k&3)
    float o = 0.0f;
    #pragma unroll
    for (int k = 0; k < D; ++k) {
        float comp = ((k & 3) == 0) ? x0 : ((k & 3) == 1) ? x1 : ((k & 3) == 2) ? x2 : x3;
        o += __shfl(comp, k >> 2) * Ws[k * D + lane];
    }
    out[(size_t)wave * D + lane] = o * norm_dst[wave];
}

// ============================================================================
// FALLBACK (round-0, proven): float-atomic scatter
// ============================================================================

__global__ void deg_kernel(const int* __restrict__ src, const int* __restrict__ dst,
                           float* __restrict__ deg, int E, int N) {
    int i = blockIdx.x * blockDim.x + threadIdx.x;
    if (i < E) {
        atomicAdd(&deg[src[i]], 1.0f);
        atomicAdd(&deg[N + dst[i]], 1.0f);
    }
}

__global__ void norm_kernel(float* __restrict__ deg, int twoN) {
    int i = blockIdx.x * blockDim.x + threadIdx.x;
    if (i < twoN) {
        float v = deg[i];
        v = v < 1.0f ? 1.0f : v;
        deg[i] = 1.0f / sqrtf(v);
    }
}

__global__ void scatter_kernel(const float* __restrict__ x, const int* __restrict__ src,
                               const int* __restrict__ dst, const float* __restrict__ norm_src,
                               float* __restrict__ agg, int E) {
    int tid = blockIdx.x * blockDim.x + threadIdx.x;
    int e = tid >> 4;
    int q = tid & 15;
    if (e < E) {
        int s = src[e];
        int d = dst[e];
        float ns = norm_src[s];
        float4 v = reinterpret_cast<const float4*>(x)[s * (D / 4) + q];
        float* o = agg + (long long)d * D + q * 4;
        atomicAdd(o + 0, v.x * ns);
        atomicAdd(o + 1, v.y * ns);
        atomicAdd(o + 2, v.z * ns);
        atomicAdd(o + 3, v.w * ns);
    }
}

__global__ __launch_bounds__(256) void gemm_kernel(float* __restrict__ out,
                                                   const float* __restrict__ W,
                                                   const float* __restrict__ norm_dst,
                                                   int N, int rows_per_block) {
    __shared__ float Ws[D * D];
    __shared__ float rowS[4][D];
    for (int i = threadIdx.x; i < D * D; i += 256) Ws[i] = W[i];

    int f   = threadIdx.x & 63;
    int sub = threadIdx.x >> 6;
    int base = blockIdx.x * rows_per_block;

    for (int r0 = 0; r0 < rows_per_block; r0 += 4) {
        int r = base + r0 + sub;
        bool valid = (r < N);
        __syncthreads();
        if (valid) rowS[sub][f] = out[(long long)r * D + f] * norm_dst[r];
        __syncthreads();
        if (valid) {
            float acc = 0.0f;
            #pragma unroll
            for (int k = 0; k < D; ++k) acc += rowS[sub][k] * Ws[k * D + f];
            out[(long long)r * D + f] = acc;
        }
    }
}

// ============================================================================
extern "C" void kernel_launch(void* const* d_in, const int* in_sizes, int n_in,
                              void* d_out, int out_size, void* d_ws, size_t ws_size,
                              hipStream_t stream) {
    const float* x   = (const float*)d_in[0];
    const float* W   = (const float*)d_in[1];
    const int*   src = (const int*)d_in[2];
    const int*   dst = (const int*)d_in[3];

    const int N = in_sizes[0] / D;   // 100000
    const int E = in_sizes[2];       // 1600000
    const int nblk = (N + SCAN_TILE - 1) / SCAN_TILE;

    // workspace layout (4-byte words)
    size_t w_norm = 0;                         // 2N floats
    size_t w_cnt  = w_norm + 2 * (size_t)N;    // 2N ints
    size_t w_offs = w_cnt  + 2 * (size_t)N;    // N+1 ints
    size_t w_cur  = w_offs + (size_t)N + 1;    // N ints
    size_t w_part = w_cur  + (size_t)N;        // SCAN_THREADS ints
    size_t w_sort = w_part + SCAN_THREADS;     // E ints
    size_t w_y    = (w_sort + (size_t)E + 3) & ~(size_t)3;  // N*D floats, 16B-aligned
    size_t need_B = (w_sort + (size_t)E) * 4;
    size_t need_A = (w_y + (size_t)N * D) * 4;

    bool csr_ok = (nblk <= SCAN_THREADS);
    bool pathA  = csr_ok && ws_size >= need_A;
    bool pathB  = csr_ok && !pathA && ws_size >= need_B;

    if (pathA || pathB) {
        float* norm       = (float*)d_ws + w_norm;
        int*   cnt        = (int*)d_ws + w_cnt;
        int*   offsets    = (int*)d_ws + w_offs;
        int*   cursor     = (int*)d_ws + w_cur;
        int*   partials   = (int*)d_ws + w_part;
        int*   sorted_src = (int*)d_ws + w_sort;
        float* y          = (float*)d_ws + w_y;
        float* out        = (float*)d_out;

        hipMemsetAsync(cnt, 0, 2 * (size_t)N * sizeof(int), stream);

        int E4 = E >> 2;
        int histblk = (E4 + 255) / 256; if (histblk < 1) histblk = 1;
        hist4_kernel<<<histblk, 256, 0, stream>>>(src, dst, cnt, E, N);
        norm_from_cnt_kernel<<<(2 * N + 255) / 256, 256, 0, stream>>>(cnt, norm, 2 * N);
        scan_blocks_kernel<<<nblk, SCAN_THREADS, 0, stream>>>(cnt + N, offsets, partials, N);
        scan_partials_kernel<<<1, SCAN_THREADS, 0, stream>>>(partials, nblk);
        add_back_kernel<<<(N + 255) / 256, 256, 0, stream>>>(offsets, cursor, partials, N, E);
        bin4_kernel<<<histblk, 256, 0, stream>>>(src, dst, cursor, sorted_src, E);

        int agg_blocks = (N + 3) / 4;   // one wave per row
        if (pathA) {
            xw_kernel<<<(N + 63) / 64, 256, 0, stream>>>(x, W, norm, y, N);
            agg_kernel<<<agg_blocks, 256, 0, stream>>>(
                (const float4*)y, offsets, sorted_src, norm + N, (float4*)out, N);
        } else {
            agg_gemm2_kernel<<<agg_blocks, 256, 0, stream>>>(
                (const float4*)x, offsets, sorted_src, norm, W, out, N);
        }
    } else {
        float* deg = (float*)d_ws;
        float* agg = (float*)d_out;

        hipMemsetAsync(deg, 0, (size_t)2 * N * sizeof(float), stream);
        hipMemsetAsync(agg, 0, (size_t)N * D * sizeof(float), stream);

        deg_kernel<<<(E + 255) / 256, 256, 0, stream>>>(src, dst, deg, E, N);
        norm_kernel<<<(2 * N + 255) / 256, 256, 0, stream>>>(deg, 2 * N);

        long long scatter_threads = (long long)E * 16;
        int scatter_blocks = (int)((scatter_threads + 255) / 256);
        scatter_kernel<<<scatter_blocks, 256, 0, stream>>>(x, src, dst, deg, agg, E);

        const int rows_per_block = 64;
        int gemm_blocks = (N + rows_per_block - 1) / rows_per_block;
        gemm_kernel<<<gemm_blocks, 256, 0, stream>>>(agg, W, deg + N, N, rows_per_block);
    }
}